// Round 2
// baseline (274.652 us; speedup 1.0000x reference)
//
#include <hip/hip_runtime.h>
#include <cstddef>

// Problem constants
#define NROWS 8192   // B*L
#define LLEN  4096
#define KNBR  32
#define DIMX  256
#define PEDIM 64
#define NH    8
#define DHD   32
#define QKVLD 768    // Q(256) | KtX(256) | VtX(256)

// ---------------------------------------------------------------------------
// Fused projection GEMM: C[r, 0:256]=x@Wq, [256:512]=x@Wk_x, [512:768]=x@Wv_x
// (Wk_x / Wv_x are the first 256 rows of Wk / Wv). 64x64 tiles, 4x4 microtile.
// ---------------------------------------------------------------------------
__global__ __launch_bounds__(256)
void qkv_gemm(const float* __restrict__ x, const float* __restrict__ Wq,
              const float* __restrict__ Wk, const float* __restrict__ Wv,
              float* __restrict__ QKV)
{
    __shared__ float As[16][64];   // [k][m]
    __shared__ float Bs[16][64];   // [k][n]
    const int t  = threadIdx.x;
    const int m0 = blockIdx.x * 64;
    const int n0 = blockIdx.y * 64;          // 0..704, selects weight matrix
    const float* Bmat = (n0 < 256) ? Wq : (n0 < 512) ? Wk : Wv;
    const int nb = n0 & 255;                 // column base within the matrix
    const int tx = t & 15, ty = t >> 4;
    const int lm = t >> 2, lk4 = (t & 3) * 4;
    const int bn = t & 63, bk = t >> 6;

    float acc[4][4];
#pragma unroll
    for (int i = 0; i < 4; ++i)
#pragma unroll
        for (int j = 0; j < 4; ++j) acc[i][j] = 0.f;

    for (int k0 = 0; k0 < DIMX; k0 += 16) {
        float4 av = *(const float4*)&x[(size_t)(m0 + lm) * DIMX + k0 + lk4];
        As[lk4 + 0][lm] = av.x;
        As[lk4 + 1][lm] = av.y;
        As[lk4 + 2][lm] = av.z;
        As[lk4 + 3][lm] = av.w;
#pragma unroll
        for (int p = 0; p < 4; ++p)
            Bs[bk + p * 4][bn] = Bmat[(size_t)(k0 + bk + p * 4) * 256 + nb + bn];
        __syncthreads();
#pragma unroll
        for (int kk = 0; kk < 16; ++kk) {
            float4 a = *(const float4*)&As[kk][ty * 4];
            float4 b = *(const float4*)&Bs[kk][tx * 4];
            float ar[4] = {a.x, a.y, a.z, a.w};
            float br[4] = {b.x, b.y, b.z, b.w};
#pragma unroll
            for (int i = 0; i < 4; ++i)
#pragma unroll
                for (int j = 0; j < 4; ++j)
                    acc[i][j] += ar[i] * br[j];
        }
        __syncthreads();
    }
#pragma unroll
    for (int i = 0; i < 4; ++i)
        *(float4*)&QKV[(size_t)(m0 + ty * 4 + i) * QKVLD + n0 + tx * 4] =
            make_float4(acc[i][0], acc[i][1], acc[i][2], acc[i][3]);
}

// ---------------------------------------------------------------------------
// Generic 64x64-tile GEMM with leading dims (for out = o @ Wout + b_out,
// where o lives in QKV[:, 0:256] with lda=768).
// ---------------------------------------------------------------------------
__global__ __launch_bounds__(256)
void gemm_nn(const float* __restrict__ A, int lda,
             const float* __restrict__ B, int ldb,
             const float* __restrict__ bias,
             float* __restrict__ C, int ldc, int Kd)
{
    __shared__ float As[16][64];
    __shared__ float Bs[16][64];
    const int t  = threadIdx.x;
    const int m0 = blockIdx.x * 64;
    const int n0 = blockIdx.y * 64;
    const int tx = t & 15, ty = t >> 4;
    const int lm = t >> 2, lk4 = (t & 3) * 4;
    const int bn = t & 63, bk = t >> 6;

    float acc[4][4];
#pragma unroll
    for (int i = 0; i < 4; ++i)
#pragma unroll
        for (int j = 0; j < 4; ++j) acc[i][j] = 0.f;

    for (int k0 = 0; k0 < Kd; k0 += 16) {
        float4 av = *(const float4*)&A[(size_t)(m0 + lm) * lda + k0 + lk4];
        As[lk4 + 0][lm] = av.x;
        As[lk4 + 1][lm] = av.y;
        As[lk4 + 2][lm] = av.z;
        As[lk4 + 3][lm] = av.w;
#pragma unroll
        for (int p = 0; p < 4; ++p)
            Bs[bk + p * 4][bn] = B[(size_t)(k0 + bk + p * 4) * ldb + n0 + bn];
        __syncthreads();
#pragma unroll
        for (int kk = 0; kk < 16; ++kk) {
            float4 a = *(const float4*)&As[kk][ty * 4];
            float4 b = *(const float4*)&Bs[kk][tx * 4];
            float ar[4] = {a.x, a.y, a.z, a.w};
            float br[4] = {b.x, b.y, b.z, b.w};
#pragma unroll
            for (int i = 0; i < 4; ++i)
#pragma unroll
                for (int j = 0; j < 4; ++j)
                    acc[i][j] += ar[i] * br[j];
        }
        __syncthreads();
    }
#pragma unroll
    for (int i = 0; i < 4; ++i) {
        const int row = m0 + ty * 4 + i;
        float ov[4];
#pragma unroll
        for (int j = 0; j < 4; ++j)
            ov[j] = acc[i][j] + (bias ? bias[n0 + tx * 4 + j] : 0.f);
        *(float4*)&C[(size_t)row * ldc + n0 + tx * 4] =
            make_float4(ov[0], ov[1], ov[2], ov[3]);
    }
}

// ---------------------------------------------------------------------------
// Fused attention: per WG = 4 rows (1 wave each).
//  T_r[h,c] = Q[h,:].Wk_pe[c, h-slice]           (rpe-side key fold, LDS)
//  logits[h,k] = Q[h,:].KtX[idx_k,h,:] + rpe[k,:].T_r[h,:]  (+ gaussian bias)
//  attn = softmax_k
//  o = sum_k attn*VtX[idx_k,:]  +  (sum_k attn*rpe[k,:]) @ Wv_pe
// o overwrites the (dead) Q slice of QKV.
// ---------------------------------------------------------------------------
__global__ __launch_bounds__(256)
void attn_fused(const float* __restrict__ QKV, const int* __restrict__ topk,
                const float* __restrict__ rpe, const float* __restrict__ dist,
                const float* __restrict__ lsig,
                const float* __restrict__ Wk, const float* __restrict__ Wv,
                float* __restrict__ O)
{
    __shared__ float Qs[4][256];          // 4 KB
    __shared__ float Tr[4][NH][PEDIM];    // 8 KB
    __shared__ float As2[4][KNBR][NH];    // 4 KB  (attn, [row][k][h])
    __shared__ float Us[4][NH][PEDIM];    // 8 KB  (u_pe)
    __shared__ float Ox[4][256];          // 4 KB  (x-side output)

    const int t    = threadIdx.x;
    const int w    = t >> 6;
    const int lane = t & 63;
    const int r0   = blockIdx.x * 4;
    const int r    = r0 + w;
    const int b    = r >> 12;             // r / LLEN
    const float scale = 0.17677669529663687f;  // 32^-0.5

    // ---- stage Q rows to LDS (wave w loads its own row, f4-coalesced) ----
    *(float4*)&Qs[w][lane * 4] = *(const float4*)&QKV[(size_t)r * QKVLD + lane * 4];
    __syncthreads();

    // ---- T_r: thread (h = t>>5, cl = t&31) handles c in {cl, cl+32} ----
    {
        const int h = t >> 5, cl = t & 31;
#pragma unroll
        for (int cc = 0; cc < 2; ++cc) {
            const int c = cl + cc * 32;
            const float4* wp = (const float4*)&Wk[(size_t)(256 + c) * 256 + h * 32];
            float4 wk[8];
#pragma unroll
            for (int j = 0; j < 8; ++j) wk[j] = wp[j];
#pragma unroll
            for (int i = 0; i < 4; ++i) {
                const float4* qp = (const float4*)&Qs[i][h * 32];
                float s = 0.f;
#pragma unroll
                for (int j = 0; j < 8; ++j) {
                    float4 q = qp[j];
                    s += q.x * wk[j].x + q.y * wk[j].y + q.z * wk[j].z + q.w * wk[j].w;
                }
                Tr[i][h][c] = s;
            }
        }
    }
    __syncthreads();

    // ---- logits + softmax: lane = (kk = lane&31, hh = lane>>5) ----
    const int kk = lane & 31, hh = lane >> 5;
    const int myidx = topk[r * KNBR + kk];
    const float* ktrow = &QKV[(size_t)(b * LLEN + myidx) * QKVLD + 256];
    const float* rrow  = &rpe[((size_t)r * KNBR + kk) * PEDIM];

    float acc4[4] = {0.f, 0.f, 0.f, 0.f};
#pragma unroll
    for (int i = 0; i < 4; ++i) {
        const int h = hh * 4 + i;
        const float4* qp = (const float4*)&Qs[w][h * 32];
        const float4* kp = (const float4*)&ktrow[h * 32];
        float s = 0.f;
#pragma unroll
        for (int j = 0; j < 8; ++j) {
            float4 q = qp[j]; float4 kv = kp[j];
            s += q.x * kv.x + q.y * kv.y + q.z * kv.z + q.w * kv.w;
        }
        acc4[i] = s;
    }
    for (int c4 = 0; c4 < 16; ++c4) {
        float4 rv = ((const float4*)rrow)[c4];
#pragma unroll
        for (int i = 0; i < 4; ++i) {
            float4 tv = *(const float4*)&Tr[w][hh * 4 + i][c4 * 4];
            acc4[i] += rv.x * tv.x + rv.y * tv.y + rv.z * tv.z + rv.w * tv.w;
        }
    }
    {
        float dd = dist[r * KNBR + kk];
        const float d2 = dd * dd;
#pragma unroll
        for (int i = 0; i < 4; ++i) {
            const int h = hh * 4 + i;
            const float sig2 = __expf(2.f * lsig[h]);
            float lg = acc4[i] * scale - d2 / (2.f * sig2);
            float mx = lg;
#pragma unroll
            for (int m = 16; m >= 1; m >>= 1)
                mx = fmaxf(mx, __shfl_xor(mx, m, 64));
            float pv = __expf(lg - mx);
            float sm = pv;
#pragma unroll
            for (int m = 16; m >= 1; m >>= 1)
                sm += __shfl_xor(sm, m, 64);
            As2[w][kk][h] = pv / sm;
        }
    }
    // (wave-local LDS: same-wave RAW is ordered; no barrier needed here)

    // ---- o_x: lane owns f4 chunk at lane*4; gather VtX rows (coalesced) ----
    {
        const int h2 = lane >> 3;
        const int* tkp = &topk[r * KNBR];
        float4 ox = make_float4(0.f, 0.f, 0.f, 0.f);
        for (int k = 0; k < KNBR; ++k) {
            const int ik = tkp[k];   // wave-uniform
            const float aw = As2[w][k][h2];
            float4 vv = *(const float4*)&QKV[(size_t)(b * LLEN + ik) * QKVLD + 512 + lane * 4];
            ox.x += aw * vv.x; ox.y += aw * vv.y;
            ox.z += aw * vv.z; ox.w += aw * vv.w;
        }
        *(float4*)&Ox[w][lane * 4] = ox;
    }

    // ---- u_pe[h, lane] = sum_k attn[h,k] * rpe[k, lane] ----
    {
        float u[NH] = {0.f, 0.f, 0.f, 0.f, 0.f, 0.f, 0.f, 0.f};
        for (int k = 0; k < KNBR; ++k) {
            const float rv = rpe[((size_t)r * KNBR + k) * PEDIM + lane];
            float4 a0 = *(const float4*)&As2[w][k][0];
            float4 a1 = *(const float4*)&As2[w][k][4];
            u[0] += a0.x * rv; u[1] += a0.y * rv; u[2] += a0.z * rv; u[3] += a0.w * rv;
            u[4] += a1.x * rv; u[5] += a1.y * rv; u[6] += a1.z * rv; u[7] += a1.w * rv;
        }
#pragma unroll
        for (int h = 0; h < NH; ++h) Us[w][h][lane] = u[h];
    }
    __syncthreads();

    // ---- o_pe + combine: thread = output column n (all 4 rows) ----
    {
        const int n = t, hn = n >> 5;
        float accp[4] = {0.f, 0.f, 0.f, 0.f};
        for (int c4 = 0; c4 < 16; ++c4) {
            const float wv0 = Wv[(size_t)(256 + c4 * 4 + 0) * 256 + n];
            const float wv1 = Wv[(size_t)(256 + c4 * 4 + 1) * 256 + n];
            const float wv2 = Wv[(size_t)(256 + c4 * 4 + 2) * 256 + n];
            const float wv3 = Wv[(size_t)(256 + c4 * 4 + 3) * 256 + n];
#pragma unroll
            for (int i = 0; i < 4; ++i) {
                float4 uv = *(const float4*)&Us[i][hn][c4 * 4];
                accp[i] += uv.x * wv0 + uv.y * wv1 + uv.z * wv2 + uv.w * wv3;
            }
        }
#pragma unroll
        for (int i = 0; i < 4; ++i)
            O[(size_t)(r0 + i) * QKVLD + n] = Ox[i][n] + accp[i];
    }
}

// ---------------------------------------------------------------------------
extern "C" void kernel_launch(void* const* d_in, const int* in_sizes, int n_in,
                              void* d_out, int out_size, void* d_ws, size_t ws_size,
                              hipStream_t stream)
{
    const float* x     = (const float*)d_in[0];
    const int*   topk  = (const int*)  d_in[1];
    const float* rpe   = (const float*)d_in[2];
    const float* dist  = (const float*)d_in[3];
    const float* Wq    = (const float*)d_in[4];
    const float* Wk    = (const float*)d_in[5];
    const float* Wv    = (const float*)d_in[6];
    const float* Wout  = (const float*)d_in[7];
    const float* b_out = (const float*)d_in[8];
    const float* lsig  = (const float*)d_in[9];
    float* out = (float*)d_out;

    float* QKV = (float*)d_ws;   // 8192 x 768 f32 = 24 MB

    // K1: QKV projections (Q | x@Wk_x | x@Wv_x)
    qkv_gemm<<<dim3(NROWS / 64, QKVLD / 64), 256, 0, stream>>>(x, Wq, Wk, Wv, QKV);
    // K2: fused attention; o overwrites Q slice of QKV
    attn_fused<<<NROWS / 4, 256, 0, stream>>>(QKV, topk, rpe, dist, lsig, Wk, Wv, QKV);
    // K3: out = o @ Wout + b_out
    gemm_nn<<<dim3(NROWS / 64, DIMX / 64), 256, 0, stream>>>(
        QKV, QKVLD, Wout, 256, b_out, out, 256, DIMX);
}